// Round 1
// baseline (1089.928 us; speedup 1.0000x reference)
//
#include <hip/hip_runtime.h>
#include <hip/hip_bf16.h>
#include <math.h>

#define N_PTS 8192
#define HD 128
#define BIGF 1e30f
#define IMAX 0x7fffffff

__device__ __forceinline__ float elu_f(float x) {
  return x > 0.0f ? x : expm1f(x);
}

// ---------------------------------------------------------------- segments
__global__ void segs_kernel(const int* __restrict__ batch32, int* __restrict__ segs) {
  __shared__ int cnt[4];
  __shared__ int is64s;
  const int t = threadIdx.x;
  if (t < 4) cnt[t] = 0;
  if (t == 0) is64s = (batch32[8191] == 0) ? 1 : 0;  // int64: high word of elem 4095
  __syncthreads();
  const int is64 = is64s;
  for (int i = t; i < N_PTS; i += blockDim.x) {
    int b = is64 ? batch32[2 * i] : batch32[i];
    atomicAdd(&cnt[b], 1);
  }
  __syncthreads();
  if (t == 0) {
    int s = 0; segs[0] = 0;
    for (int b = 0; b < 4; ++b) { s += cnt[b]; segs[b + 1] = s; }
  }
}

// ---------------------------------------------------------------- encode
// out = elu(elu(x@We1+be1)@We2+be2), 16 rows/block, 128 threads (one per out ch)
__global__ __launch_bounds__(128) void encode_kernel(
    const float* __restrict__ x_lc,
    const float* __restrict__ We1, const float* __restrict__ be1,
    const float* __restrict__ We2, const float* __restrict__ be2,
    float* __restrict__ out) {
  __shared__ float xr[16 * 15];
  __shared__ float h1[16][128];
  const int r0 = blockIdx.x * 16;
  const int c = threadIdx.x;
  for (int tt = c; tt < 240; tt += 128) xr[tt] = x_lc[r0 * 15 + tt];
  __syncthreads();
  float acc[16];
#pragma unroll
  for (int r = 0; r < 16; ++r) acc[r] = be1[c];
  for (int j = 0; j < 15; ++j) {
    float w = We1[j * 128 + c];
#pragma unroll
    for (int r = 0; r < 16; ++r) acc[r] = fmaf(xr[r * 15 + j], w, acc[r]);
  }
#pragma unroll
  for (int r = 0; r < 16; ++r) h1[r][c] = elu_f(acc[r]);
  __syncthreads();
#pragma unroll
  for (int r = 0; r < 16; ++r) acc[r] = be2[c];
  for (int j0 = 0; j0 < 128; j0 += 4) {
    float w0 = We2[(j0 + 0) * 128 + c];
    float w1 = We2[(j0 + 1) * 128 + c];
    float w2 = We2[(j0 + 2) * 128 + c];
    float w3 = We2[(j0 + 3) * 128 + c];
#pragma unroll
    for (int r = 0; r < 16; ++r) {
      float4 h = *(const float4*)&h1[r][j0];
      acc[r] = fmaf(h.x, w0, acc[r]);
      acc[r] = fmaf(h.y, w1, acc[r]);
      acc[r] = fmaf(h.z, w2, acc[r]);
      acc[r] = fmaf(h.w, w3, acc[r]);
    }
  }
#pragma unroll
  for (int r = 0; r < 16; ++r) out[(r0 + r) * 128 + c] = elu_f(acc[r]);
}

// ---------------------------------------------------------------- row norms
__global__ __launch_bounds__(256) void rownorm_kernel(const float* __restrict__ X,
                                                      float* __restrict__ sq) {
  const int r = blockIdx.x * 256 + threadIdx.x;
  const float4* row = (const float4*)(X + (size_t)r * 128);
  float s = 0.0f;
#pragma unroll
  for (int c = 0; c < 32; ++c) {
    float4 v = row[c];
    s = fmaf(v.x, v.x, s); s = fmaf(v.y, v.y, s);
    s = fmaf(v.z, v.z, s); s = fmaf(v.w, v.w, s);
  }
  sq[r] = s;
}

// ---------------------------------------------------------------- P/Q prep
// P = Wtop - Wbot, Q = Wbot  (concat([xi, xj-xi])@W == xi@P + xj@Q)
__global__ void prep_pq(const float* __restrict__ W, float* __restrict__ P,
                        float* __restrict__ Q) {
  const int id = blockIdx.x * 256 + threadIdx.x;  // 16384
  const int k = id >> 7, c = id & 127;
  float top = W[k * 128 + c];
  float bot = W[(k + 128) * 128 + c];
  P[id] = top - bot;
  Q[id] = bot;
}

// ---------------------------------------------------------------- knn
__device__ __forceinline__ bool lex_less(float da, int ia, float db, int ib) {
  return (da < db) || ((da == db) && (ia < ib));
}
__device__ __forceinline__ void ins4(float d[4], int ix[4], float nd, int ni) {
  if (lex_less(nd, ni, d[3], ix[3])) {
    d[3] = nd; ix[3] = ni;
    if (lex_less(d[3], ix[3], d[2], ix[2])) { float td=d[3];d[3]=d[2];d[2]=td; int ti=ix[3];ix[3]=ix[2];ix[2]=ti; }
    if (lex_less(d[2], ix[2], d[1], ix[1])) { float td=d[2];d[2]=d[1];d[1]=td; int ti=ix[2];ix[2]=ix[1];ix[1]=ti; }
    if (lex_less(d[1], ix[1], d[0], ix[0])) { float td=d[1];d[1]=d[0];d[0]=td; int ti=ix[1];ix[1]=ix[0];ix[0]=ti; }
  }
}

#define ACC4(A, B, ai, bi) \
  acc[ai][bi] = fmaf(A.x, B.x, fmaf(A.y, B.y, fmaf(A.z, B.z, fmaf(A.w, B.w, acc[ai][bi]))));

// 64 i-rows per i-tile, j-range split 4 ways across blocks. 256 threads:
// thread = (ig = t&15, jg = t>>4); 4 strided i rows x 4 strided j rows.
__global__ __launch_bounds__(256) void knn_kernel(
    const float* __restrict__ X, const int* __restrict__ segs,
    const float* __restrict__ sq, float* __restrict__ candD,
    int* __restrict__ candI) {
  __shared__ float xi[64][132];                 // 33792 B (132*4=528, 16B-aligned rows)
  __shared__ __align__(16) char smj[64 * 132 * 4];  // xj / merge overlay
  __shared__ float sqj[64];
  float (*xj)[132] = (float(*)[132])smj;
  float (*cd)[65] = (float(*)[65])smj;          // 64*65*4 = 16640
  int (*ci)[65] = (int(*)[65])(smj + 64 * 65 * 4);

  const int t = threadIdx.x;
  const int ib = blockIdx.x >> 2;
  const int hs = blockIdx.x & 3;
  const int i0 = ib * 64;

  // stage xi tile
#pragma unroll
  for (int v = 0; v < 8; ++v) {
    int lin = t + v * 256;
    int r = lin >> 5, c4 = lin & 31;
    float4 val = *(const float4*)&X[(size_t)(i0 + r) * 128 + c4 * 4];
    *(float4*)&xi[r][c4 * 4] = val;
  }

  // per-i segment bounds (4 strided rows per thread)
  const int ig = t & 15;
  const int jg = t >> 4;
  int jloI[4], jhiI[4], iG[4];
#pragma unroll
  for (int a = 0; a < 4; ++a) {
    iG[a] = i0 + ig + a * 16;
    int lo = 0, hi = 0;
#pragma unroll
    for (int b = 0; b < 4; ++b) {
      int s = segs[b], e = segs[b + 1];
      if (iG[a] >= s && iG[a] < e) { lo = s; hi = e; }
    }
    jloI[a] = lo; jhiI[a] = hi;
  }
  int jlo_blk = 0, jhi_blk = 0;
  {
    int bf = 0, bl = 0;
#pragma unroll
    for (int b = 0; b < 4; ++b) {
      int s = segs[b], e = segs[b + 1];
      if (i0 >= s && i0 < e) bf = b;
      if (i0 + 63 >= s && i0 + 63 < e) bl = b;
    }
    jlo_blk = segs[bf]; jhi_blk = segs[bl + 1];
  }
  const int len = jhi_blk - jlo_blk;
  const int qlen = (len + 3) >> 2;
  const int jstart = jlo_blk + hs * qlen;
  const int jend = min(jstart + qlen, jhi_blk);

  float bd[4][4]; int bi_[4][4];
#pragma unroll
  for (int a = 0; a < 4; ++a)
#pragma unroll
    for (int q = 0; q < 4; ++q) { bd[a][q] = BIGF; bi_[a][q] = IMAX; }

  for (int jt = jstart; jt < jend; jt += 64) {
    __syncthreads();
#pragma unroll
    for (int v = 0; v < 8; ++v) {
      int lin = t + v * 256;
      int r = lin >> 5, c4 = lin & 31;
      int jgl = jt + r;
      float4 val = make_float4(0.f, 0.f, 0.f, 0.f);
      if (jgl < jend) val = *(const float4*)&X[(size_t)jgl * 128 + c4 * 4];
      *(float4*)&xj[r][c4 * 4] = val;
    }
    if (t < 64) sqj[t] = (jt + t < jend) ? sq[jt + t] : 0.0f;
    __syncthreads();

    float acc[4][4] = {};
#pragma unroll 8
    for (int c4 = 0; c4 < 32; ++c4) {
      const int cc = c4 * 4;
      float4 xa0 = *(const float4*)&xi[ig][cc];
      float4 xa1 = *(const float4*)&xi[ig + 16][cc];
      float4 xa2 = *(const float4*)&xi[ig + 32][cc];
      float4 xa3 = *(const float4*)&xi[ig + 48][cc];
      float4 xb0 = *(const float4*)&xj[jg][cc];
      float4 xb1 = *(const float4*)&xj[jg + 16][cc];
      float4 xb2 = *(const float4*)&xj[jg + 32][cc];
      float4 xb3 = *(const float4*)&xj[jg + 48][cc];
      ACC4(xa0, xb0, 0, 0); ACC4(xa0, xb1, 0, 1); ACC4(xa0, xb2, 0, 2); ACC4(xa0, xb3, 0, 3);
      ACC4(xa1, xb0, 1, 0); ACC4(xa1, xb1, 1, 1); ACC4(xa1, xb2, 1, 2); ACC4(xa1, xb3, 1, 3);
      ACC4(xa2, xb0, 2, 0); ACC4(xa2, xb1, 2, 1); ACC4(xa2, xb2, 2, 2); ACC4(xa2, xb3, 2, 3);
      ACC4(xa3, xb0, 3, 0); ACC4(xa3, xb1, 3, 1); ACC4(xa3, xb2, 3, 2); ACC4(xa3, xb3, 3, 3);
    }
#pragma unroll
    for (int b = 0; b < 4; ++b) {
      int jrow = jg + b * 16;
      int jgl = jt + jrow;
      float sj = sqj[jrow];
#pragma unroll
      for (int a = 0; a < 4; ++a) {
        bool valid = (jgl < jend) && (jgl >= jloI[a]) && (jgl < jhiI[a]) && (jgl != iG[a]);
        float key = valid ? fmaf(-2.0f, acc[a][b], sj) : BIGF;
        ins4(bd[a], bi_[a], key, valid ? jgl : IMAX);
      }
    }
  }

  __syncthreads();
#pragma unroll
  for (int a = 0; a < 4; ++a) {
    int irow = ig + a * 16;
#pragma unroll
    for (int q = 0; q < 4; ++q) {
      cd[irow][jg * 4 + q] = bd[a][q];
      ci[irow][jg * 4 + q] = bi_[a][q];
    }
  }
  __syncthreads();
  if (t < 64) {
    float d[4] = {BIGF, BIGF, BIGF, BIGF};
    int ix[4] = {IMAX, IMAX, IMAX, IMAX};
    for (int e = 0; e < 64; ++e) ins4(d, ix, cd[t][e], ci[t][e]);
    const int i = i0 + t;
#pragma unroll
    for (int q = 0; q < 4; ++q) {
      candD[((size_t)hs * N_PTS + i) * 4 + q] = d[q];
      candI[((size_t)hs * N_PTS + i) * 4 + q] = ix[q];
    }
  }
}

__global__ __launch_bounds__(256) void knn_merge(const float* __restrict__ candD,
                                                 const int* __restrict__ candI,
                                                 int* __restrict__ idx_out) {
  const int i = blockIdx.x * 256 + threadIdx.x;
  float d[4] = {BIGF, BIGF, BIGF, BIGF};
  int ix[4] = {IMAX, IMAX, IMAX, IMAX};
#pragma unroll
  for (int h = 0; h < 4; ++h) {
    float4 dd = *(const float4*)&candD[((size_t)h * N_PTS + i) * 4];
    int4 ii = *(const int4*)&candI[((size_t)h * N_PTS + i) * 4];
    ins4(d, ix, dd.x, ii.x); ins4(d, ix, dd.y, ii.y);
    ins4(d, ix, dd.z, ii.z); ins4(d, ix, dd.w, ii.w);
  }
#pragma unroll
  for (int q = 0; q < 4; ++q) {
    int v = ix[q];
    if (v > N_PTS - 1) v = 0;  // unreachable for real segment sizes; OOB guard
    idx_out[i * 4 + q] = v;
  }
}

// ---------------------------------------------------------------- U/V GEMMs
// U = X@P + bias (bias folded), V = X@Q. 16 rows/block, 256 threads.
__global__ __launch_bounds__(256) void uv_kernel(
    const float* __restrict__ X, const float* __restrict__ P,
    const float* __restrict__ Q, const float* __restrict__ bias,
    float* __restrict__ U, float* __restrict__ V) {
  __shared__ float xs[16][129];
  const int t = threadIdx.x;
  const int r0 = blockIdx.x * 16;
#pragma unroll
  for (int v = 0; v < 2; ++v) {
    int lin = t + v * 256;
    int r = lin >> 5, c4 = lin & 31;
    float4 val = *(const float4*)&X[(size_t)(r0 + r) * 128 + c4 * 4];
    xs[r][c4 * 4 + 0] = val.x; xs[r][c4 * 4 + 1] = val.y;
    xs[r][c4 * 4 + 2] = val.z; xs[r][c4 * 4 + 3] = val.w;
  }
  __syncthreads();
  const int cg = t & 31, rg = t >> 5;  // rows rg*2, rg*2+1
  const int c0 = cg * 4;
  float4 b4 = *(const float4*)&bias[c0];
  float4 u0 = b4, u1 = b4;
  float4 v0 = make_float4(0, 0, 0, 0), v1 = make_float4(0, 0, 0, 0);
#pragma unroll 8
  for (int k = 0; k < 128; ++k) {
    float4 p = *(const float4*)&P[k * 128 + c0];
    float4 q = *(const float4*)&Q[k * 128 + c0];
    float xa = xs[rg * 2 + 0][k], xb = xs[rg * 2 + 1][k];
    u0.x = fmaf(xa, p.x, u0.x); u0.y = fmaf(xa, p.y, u0.y);
    u0.z = fmaf(xa, p.z, u0.z); u0.w = fmaf(xa, p.w, u0.w);
    u1.x = fmaf(xb, p.x, u1.x); u1.y = fmaf(xb, p.y, u1.y);
    u1.z = fmaf(xb, p.z, u1.z); u1.w = fmaf(xb, p.w, u1.w);
    v0.x = fmaf(xa, q.x, v0.x); v0.y = fmaf(xa, q.y, v0.y);
    v0.z = fmaf(xa, q.z, v0.z); v0.w = fmaf(xa, q.w, v0.w);
    v1.x = fmaf(xb, q.x, v1.x); v1.y = fmaf(xb, q.y, v1.y);
    v1.z = fmaf(xb, q.z, v1.z); v1.w = fmaf(xb, q.w, v1.w);
  }
  const int ra = r0 + rg * 2, rb = ra + 1;
  *(float4*)&U[(size_t)ra * 128 + c0] = u0;
  *(float4*)&U[(size_t)rb * 128 + c0] = u1;
  *(float4*)&V[(size_t)ra * 128 + c0] = v0;
  *(float4*)&V[(size_t)rb * 128 + c0] = v1;
}

// ---------------------------------------------------------------- BN stats
__global__ __launch_bounds__(256) void stats_kernel(
    const float* __restrict__ U, const float* __restrict__ V,
    const int* __restrict__ idx, float* __restrict__ stats) {
  __shared__ float ps[2][128], ps2[2][128];
  const int t = threadIdx.x;
  const int c = t & 127, half = t >> 7;
  const int r0 = blockIdx.x * 64 + half * 32;
  float s = 0.0f, s2 = 0.0f;
  for (int rr = 0; rr < 32; ++rr) {
    const int i = r0 + rr;
    const float u = U[(size_t)i * 128 + c];
    const int4 jj = *(const int4*)&idx[i * 4];
    float h0 = elu_f(u + V[(size_t)jj.x * 128 + c]);
    float h1 = elu_f(u + V[(size_t)jj.y * 128 + c]);
    float h2 = elu_f(u + V[(size_t)jj.z * 128 + c]);
    float h3 = elu_f(u + V[(size_t)jj.w * 128 + c]);
    s += h0 + h1 + h2 + h3;
    s2 = fmaf(h0, h0, s2); s2 = fmaf(h1, h1, s2);
    s2 = fmaf(h2, h2, s2); s2 = fmaf(h3, h3, s2);
  }
  ps[half][c] = s; ps2[half][c] = s2;
  __syncthreads();
  if (t < 128) {
    atomicAdd(&stats[t], ps[0][t] + ps[1][t]);
    atomicAdd(&stats[128 + t], ps2[0][t] + ps2[1][t]);
  }
}

__global__ void finalize_kernel(const float* __restrict__ stats,
                                const float* __restrict__ g,
                                const float* __restrict__ bt,
                                float* __restrict__ sAB) {
  const int c = threadIdx.x;
  const float inv_n = 1.0f / 32768.0f;
  float mean = stats[c] * inv_n;
  float var = stats[128 + c] * inv_n - mean * mean;
  float inv = 1.0f / sqrtf(var + 1e-5f);
  float sA = g[c] * inv;
  sAB[c] = sA;
  sAB[128 + c] = bt[c] - mean * sA;
}

// ---------------------------------------------------------------- pass2: BN + max + residual
__global__ __launch_bounds__(256) void pass2_kernel(
    const float* __restrict__ U, const float* __restrict__ V,
    const int* __restrict__ idx, const float* __restrict__ sAB,
    const float* __restrict__ res, float* __restrict__ out) {
  const int t = threadIdx.x;
  const int c = t & 127, half = t >> 7;
  const int r0 = blockIdx.x * 64 + half * 32;
  const float sA = sAB[c], sB = sAB[128 + c];
  for (int rr = 0; rr < 32; ++rr) {
    const int i = r0 + rr;
    const float u = U[(size_t)i * 128 + c];
    const int4 jj = *(const int4*)&idx[i * 4];
    float m = fmaf(elu_f(u + V[(size_t)jj.x * 128 + c]), sA, sB);
    m = fmaxf(m, fmaf(elu_f(u + V[(size_t)jj.y * 128 + c]), sA, sB));
    m = fmaxf(m, fmaf(elu_f(u + V[(size_t)jj.z * 128 + c]), sA, sB));
    m = fmaxf(m, fmaf(elu_f(u + V[(size_t)jj.w * 128 + c]), sA, sB));
    if (res != nullptr) m += res[(size_t)i * 128 + c];
    out[(size_t)i * 128 + c] = m;
  }
}

// ---------------------------------------------------------------- output MLP
__global__ __launch_bounds__(256) void mlp_kernel(
    const float* __restrict__ F,
    const float* __restrict__ Wo1, const float* __restrict__ bo1,
    const float* __restrict__ Wo2, const float* __restrict__ bo2,
    const float* __restrict__ Wo3, const float* __restrict__ bo3,
    float* __restrict__ out) {
  __shared__ float xs[8][128];
  __shared__ float o1s[8][33];
  __shared__ float o2s[8][17];
  const int t = threadIdx.x;
  const int r0 = blockIdx.x * 8;
  {
    int r = t >> 5, c4 = t & 31;
    *(float4*)&xs[r][c4 * 4] = *(const float4*)&F[(size_t)(r0 + r) * 128 + c4 * 4];
  }
  __syncthreads();
  const int r = t >> 5, c = t & 31;
  {
    float acc = bo1[c];
    for (int j = 0; j < 128; ++j) acc = fmaf(xs[r][j], Wo1[j * 32 + c], acc);
    o1s[r][c] = elu_f(acc);
  }
  __syncthreads();
  if (c < 16) {
    float acc = bo2[c];
#pragma unroll
    for (int j = 0; j < 32; ++j) acc = fmaf(o1s[r][j], Wo2[j * 16 + c], acc);
    o2s[r][c] = elu_f(acc);
  }
  __syncthreads();
  if (c < 8) {
    float acc = bo3[c];
#pragma unroll
    for (int j = 0; j < 16; ++j) acc = fmaf(o2s[r][j], Wo3[j * 8 + c], acc);
    out[(size_t)(r0 + r) * 8 + c] = acc;
  }
}

// ---------------------------------------------------------------- launch
extern "C" void kernel_launch(void* const* d_in, const int* in_sizes, int n_in,
                              void* d_out, int out_size, void* d_ws, size_t ws_size,
                              hipStream_t stream) {
  (void)in_sizes; (void)n_in; (void)out_size; (void)ws_size;
  const float* x_lc = (const float*)d_in[0];
  const int* batch = (const int*)d_in[1];
  const float* We1 = (const float*)d_in[2];
  const float* be1 = (const float*)d_in[3];
  const float* We2 = (const float*)d_in[4];
  const float* be2 = (const float*)d_in[5];
  const float* Wc[3] = {(const float*)d_in[6], (const float*)d_in[10], (const float*)d_in[14]};
  const float* bc[3] = {(const float*)d_in[7], (const float*)d_in[11], (const float*)d_in[15]};
  const float* gg[3] = {(const float*)d_in[8], (const float*)d_in[12], (const float*)d_in[16]};
  const float* bt[3] = {(const float*)d_in[9], (const float*)d_in[13], (const float*)d_in[17]};
  const float* Wo1 = (const float*)d_in[18]; const float* bo1 = (const float*)d_in[19];
  const float* Wo2 = (const float*)d_in[20]; const float* bo2 = (const float*)d_in[21];
  const float* Wo3 = (const float*)d_in[22]; const float* bo3 = (const float*)d_in[23];
  float* out = (float*)d_out;

  float* ws = (float*)d_ws;
  float* featA = ws;                          // 8192*128
  float* featB = featA + N_PTS * HD;
  float* U = featB + N_PTS * HD;
  float* V = U + N_PTS * HD;
  float* sq = V + N_PTS * HD;                 // 8192
  float* Pb = sq + N_PTS;                     // 16384
  float* Qb = Pb + 16384;
  float* stats = Qb + 16384;                  // 256
  float* sAB = stats + 256;                   // 256
  float* candD = sAB + 256;                   // 4*8192*4
  int* candI = (int*)(candD + 4 * N_PTS * 4);
  int* idxb = candI + 4 * N_PTS * 4;          // 8192*4
  int* segs = idxb + N_PTS * 4;               // 5

  segs_kernel<<<1, 256, 0, stream>>>(batch, segs);
  encode_kernel<<<512, 128, 0, stream>>>(x_lc, We1, be1, We2, be2, featA);

  float* bufs[2] = {featA, featB};
  int cur = 0;
  for (int cc = 0; cc < 3; ++cc) {
    const float* Xc = bufs[cur];
    float* Onext = bufs[cur ^ 1];
    const float* rs = (cc == 0) ? nullptr : Xc;

    prep_pq<<<64, 256, 0, stream>>>(Wc[cc], Pb, Qb);
    rownorm_kernel<<<32, 256, 0, stream>>>(Xc, sq);
    knn_kernel<<<512, 256, 0, stream>>>(Xc, segs, sq, candD, candI);
    knn_merge<<<32, 256, 0, stream>>>(candD, candI, idxb);
    uv_kernel<<<512, 256, 0, stream>>>(Xc, Pb, Qb, bc[cc], U, V);
    hipMemsetAsync(stats, 0, 256 * sizeof(float), stream);
    stats_kernel<<<128, 256, 0, stream>>>(U, V, idxb, stats);
    finalize_kernel<<<1, 128, 0, stream>>>(stats, gg[cc], bt[cc], sAB);
    pass2_kernel<<<128, 256, 0, stream>>>(U, V, idxb, sAB, rs, Onext);
    cur ^= 1;
  }

  mlp_kernel<<<1024, 256, 0, stream>>>(bufs[cur], Wo1, bo1, Wo2, bo2, Wo3, bo3, out);
}

// Round 5
// 752.276 us; speedup vs baseline: 1.4488x; 1.4488x over previous
//
#include <hip/hip_runtime.h>
#include <hip/hip_bf16.h>
#include <math.h>

#define N_PTS 8192
#define HD 128
#define BIGF 1e30f
#define IMAX 0x7fffffff

typedef __bf16 bf16x8 __attribute__((ext_vector_type(8)));
typedef float f32x4 __attribute__((ext_vector_type(4)));

__device__ __forceinline__ float elu_f(float x) {
  return x > 0.0f ? x : expm1f(x);
}

__device__ __forceinline__ void gload16(const void* g, const void* l) {
  __builtin_amdgcn_global_load_lds((const __attribute__((address_space(1))) unsigned int*)g,
                                   (__attribute__((address_space(3))) unsigned int*)l,
                                   16, 0, 0);
}

// ---------------------------------------------------------------- segments
__global__ void segs_kernel(const int* __restrict__ batch32, int* __restrict__ segs) {
  __shared__ int cnt[4];
  __shared__ int is64s;
  const int t = threadIdx.x;
  if (t < 4) cnt[t] = 0;
  if (t == 0) is64s = (batch32[8191] == 0) ? 1 : 0;  // int64: high word of elem 4095
  __syncthreads();
  const int is64 = is64s;
  for (int i = t; i < N_PTS; i += blockDim.x) {
    int b = is64 ? batch32[2 * i] : batch32[i];
    atomicAdd(&cnt[b], 1);  // integer atomic: exact, order-independent
  }
  __syncthreads();
  if (t == 0) {
    int s = 0; segs[0] = 0;
    for (int b = 0; b < 4; ++b) { s += cnt[b]; segs[b + 1] = s; }
  }
}

// ---------------------------------------------------------------- encode
__global__ __launch_bounds__(128) void encode_kernel(
    const float* __restrict__ x_lc,
    const float* __restrict__ We1, const float* __restrict__ be1,
    const float* __restrict__ We2, const float* __restrict__ be2,
    float* __restrict__ out) {
  __shared__ float xr[16 * 15];
  __shared__ float h1[16][128];
  const int r0 = blockIdx.x * 16;
  const int c = threadIdx.x;
  for (int tt = c; tt < 240; tt += 128) xr[tt] = x_lc[r0 * 15 + tt];
  __syncthreads();
  float acc[16];
#pragma unroll
  for (int r = 0; r < 16; ++r) acc[r] = be1[c];
  for (int j = 0; j < 15; ++j) {
    float w = We1[j * 128 + c];
#pragma unroll
    for (int r = 0; r < 16; ++r) acc[r] = fmaf(xr[r * 15 + j], w, acc[r]);
  }
#pragma unroll
  for (int r = 0; r < 16; ++r) h1[r][c] = elu_f(acc[r]);
  __syncthreads();
#pragma unroll
  for (int r = 0; r < 16; ++r) acc[r] = be2[c];
  for (int j0 = 0; j0 < 128; j0 += 4) {
    float w0 = We2[(j0 + 0) * 128 + c];
    float w1 = We2[(j0 + 1) * 128 + c];
    float w2 = We2[(j0 + 2) * 128 + c];
    float w3 = We2[(j0 + 3) * 128 + c];
#pragma unroll
    for (int r = 0; r < 16; ++r) {
      float4 h = *(const float4*)&h1[r][j0];
      acc[r] = fmaf(h.x, w0, acc[r]);
      acc[r] = fmaf(h.y, w1, acc[r]);
      acc[r] = fmaf(h.z, w2, acc[r]);
      acc[r] = fmaf(h.w, w3, acc[r]);
    }
  }
#pragma unroll
  for (int r = 0; r < 16; ++r) out[(r0 + r) * 128 + c] = elu_f(acc[r]);
}

// ---------------------------------------------------------------- row norms
__global__ __launch_bounds__(256) void rownorm_kernel(const float* __restrict__ X,
                                                      float* __restrict__ sq) {
  const int r = blockIdx.x * 256 + threadIdx.x;
  const float4* row = (const float4*)(X + (size_t)r * 128);
  float s = 0.0f;
#pragma unroll
  for (int c = 0; c < 32; ++c) {
    float4 v = row[c];
    s = fmaf(v.x, v.x, s); s = fmaf(v.y, v.y, s);
    s = fmaf(v.z, v.z, s); s = fmaf(v.w, v.w, s);
  }
  sq[r] = s;
}

// ---------------------------------------------------------------- bf16 split
__global__ __launch_bounds__(256) void tobf16_kernel(const float* __restrict__ X,
                                                     ushort* __restrict__ Xhi,
                                                     ushort* __restrict__ Xlo) {
  const int i = blockIdx.x * 256 + threadIdx.x;  // grid 1024, 4 elems each
  float4 v = *(const float4*)&X[i * 4];
  float vv[4] = {v.x, v.y, v.z, v.w};
  ushort h[4], l[4];
#pragma unroll
  for (int e = 0; e < 4; ++e) {
    __hip_bfloat16 hb = __float2bfloat16(vv[e]);
    float hf = __bfloat162float(hb);
    __hip_bfloat16 lb = __float2bfloat16(vv[e] - hf);
    h[e] = *(ushort*)&hb; l[e] = *(ushort*)&lb;
  }
  *(ushort4*)&Xhi[i * 4] = make_ushort4(h[0], h[1], h[2], h[3]);
  *(ushort4*)&Xlo[i * 4] = make_ushort4(l[0], l[1], l[2], l[3]);
}

// ---------------------------------------------------------------- P/Q prep
__global__ void prep_pq(const float* __restrict__ W, float* __restrict__ P,
                        float* __restrict__ Q) {
  const int id = blockIdx.x * 256 + threadIdx.x;  // 16384
  const int k = id >> 7, c = id & 127;
  float top = W[k * 128 + c];
  float bot = W[(k + 128) * 128 + c];
  P[id] = top - bot;
  Q[id] = bot;
}

// ---------------------------------------------------------------- knn helpers
__device__ __forceinline__ bool lex_less(float da, int ia, float db, int ib) {
  return (da < db) || ((da == db) && (ia < ib));
}
__device__ __forceinline__ void ins4(float d[4], int ix[4], float nd, int ni) {
  if (lex_less(nd, ni, d[3], ix[3])) {
    d[3] = nd; ix[3] = ni;
    if (lex_less(d[3], ix[3], d[2], ix[2])) { float td=d[3];d[3]=d[2];d[2]=td; int ti=ix[3];ix[3]=ix[2];ix[2]=ti; }
    if (lex_less(d[2], ix[2], d[1], ix[1])) { float td=d[2];d[2]=d[1];d[1]=td; int ti=ix[2];ix[2]=ix[1];ix[1]=ti; }
    if (lex_less(d[1], ix[1], d[0], ix[0])) { float td=d[1];d[1]=d[0];d[0]=td; int ti=ix[1];ix[1]=ix[0];ix[0]=ti; }
  }
}

// ---------------------------------------------------------------- knn via MFMA
// Block: 32 i-rows (ib) x 1 j-quarter (hs). 256 threads = 4 waves; wave w owns
// j-sub-tile w of each 64-j LDS tile. D[j][i] = xj . xi^T via 3-term bf16 split.
// LDS tiles: [64 rows][16 chunks of 16B] hi then lo, chunk-swizzled c16^(row&7).
__global__ __launch_bounds__(256, 2) void knn_mfma_kernel(
    const ushort* __restrict__ Xhi, const ushort* __restrict__ Xlo,
    const int* __restrict__ segs, const float* __restrict__ sq,
    float* __restrict__ candD, int* __restrict__ candI) {
  __shared__ __align__(16) char bufA[32768];
  __shared__ __align__(16) char bufB[32768];
  __shared__ float sqj[2][64];

  const int t = threadIdx.x;
  const int w = t >> 6;
  const int lane = t & 63;
  const int ib = blockIdx.x >> 2;
  const int hs = blockIdx.x & 3;
  const int i0 = ib * 32;

  // staging constants: chunk id = c*256 + w*64 + lane; row = c*16 + rb; c16 = lane&15
  const int rb = w * 4 + (lane >> 4);          // 0..15
  const int c16l = (lane & 15) ^ (rb & 7);     // pre-swizzled source chunk
  const int coff = c16l * 8;                   // ushort offset within row

  // ---- stage xi (32 rows, hi@0 lo@8192) into bufB
#pragma unroll
  for (int c = 0; c < 4; ++c) {
    const ushort* base = (c < 2) ? Xhi : Xlo;
    const ushort* src = base + ((size_t)(i0 + (c & 1) * 16 + rb) * HD + coff);
    gload16(src, bufB + c * 4096 + w * 1024);
  }

  // per-i segment bounds
  int jloI[2], jhiI[2], iG[2];
#pragma unroll
  for (int a = 0; a < 2; ++a) {
    iG[a] = i0 + a * 16 + (lane & 15);
    int lo = 0, hi = 0;
#pragma unroll
    for (int b = 0; b < 4; ++b) {
      int s = segs[b], e = segs[b + 1];
      if (iG[a] >= s && iG[a] < e) { lo = s; hi = e; }
    }
    jloI[a] = lo; jhiI[a] = hi;
  }
  int jlo_blk = 0, jhi_blk = 0;
  {
    int bf = 0, bl = 0;
#pragma unroll
    for (int b = 0; b < 4; ++b) {
      int s = segs[b], e = segs[b + 1];
      if (i0 >= s && i0 < e) bf = b;
      if (i0 + 31 >= s && i0 + 31 < e) bl = b;
    }
    jlo_blk = segs[bf]; jhi_blk = segs[bl + 1];
  }
  const int len = jhi_blk - jlo_blk;
  const int qlen = (len + 3) >> 2;
  const int jstart = jlo_blk + hs * qlen;
  const int jend = min(jstart + qlen, jhi_blk);
  const int niter = (jend > jstart) ? ((jend - jstart + 63) >> 6) : 0;

  __syncthreads();  // xi staged (barrier drains vmcnt)

  // ---- hoist B-fragments (xi): 2 ti x 4 kk x {hi,lo}
  bf16x8 bh[2][4], bl_[2][4];
  {
    const int r15 = lane & 15;
    const int ch = lane >> 4;
#pragma unroll
    for (int ti = 0; ti < 2; ++ti) {
      int row = ti * 16 + r15;
      int sw = row & 7;
#pragma unroll
      for (int kk = 0; kk < 4; ++kk) {
        int off = row * 256 + (((kk * 4 + ch) ^ sw) * 16);
        bh[ti][kk] = *(const bf16x8*)(bufB + off);
        bl_[ti][kk] = *(const bf16x8*)(bufB + 8192 + off);
      }
    }
  }
  asm volatile("s_waitcnt lgkmcnt(0)" ::: "memory");

  // ---- issue tile 0 into bufA
  if (niter > 0) {
#pragma unroll
    for (int c = 0; c < 8; ++c) {
      const ushort* base = (c < 4) ? Xhi : Xlo;
      int rg = jstart + (c & 3) * 16 + rb;
      if (rg > N_PTS - 1) rg = N_PTS - 1;
      gload16(base + ((size_t)rg * HD + coff), bufA + c * 4096 + w * 1024);
    }
    if (t < 64) sqj[0][t] = sq[min(jstart + t, N_PTS - 1)];
  }

  float bd[2][4]; int bix[2][4];
#pragma unroll
  for (int a = 0; a < 2; ++a)
#pragma unroll
    for (int q = 0; q < 4; ++q) { bd[a][q] = BIGF; bix[a][q] = IMAX; }

  int cur = 0;
  for (int it = 0; it < niter; ++it) {
    const int jt = jstart + (it << 6);
    __syncthreads();  // tile[cur] loads drained + all waves synced
    if (it + 1 < niter) {
      char* dst = cur ? bufA : bufB;
      const int jn = jt + 64;
#pragma unroll
      for (int c = 0; c < 8; ++c) {
        const ushort* base = (c < 4) ? Xhi : Xlo;
        int rg = jn + (c & 3) * 16 + rb;
        if (rg > N_PTS - 1) rg = N_PTS - 1;
        gload16(base + ((size_t)rg * HD + coff), dst + c * 4096 + w * 1024);
      }
      if (t < 64) sqj[cur ^ 1][t] = sq[min(jn + t, N_PTS - 1)];
    }
    const char* bx = cur ? bufB : bufA;

    const int rA = w * 16 + (lane & 15);
    const int swA = rA & 7;
    f32x4 acc0 = {0.f, 0.f, 0.f, 0.f}, acc1 = {0.f, 0.f, 0.f, 0.f};
#pragma unroll
    for (int kk = 0; kk < 4; ++kk) {
      int off = rA * 256 + (((kk * 4 + (lane >> 4)) ^ swA) * 16);
      bf16x8 ahi = *(const bf16x8*)(bx + off);
      bf16x8 alo = *(const bf16x8*)(bx + 16384 + off);
      acc0 = __builtin_amdgcn_mfma_f32_16x16x32_bf16(ahi, bh[0][kk], acc0, 0, 0, 0);
      acc1 = __builtin_amdgcn_mfma_f32_16x16x32_bf16(ahi, bh[1][kk], acc1, 0, 0, 0);
      acc0 = __builtin_amdgcn_mfma_f32_16x16x32_bf16(ahi, bl_[0][kk], acc0, 0, 0, 0);
      acc1 = __builtin_amdgcn_mfma_f32_16x16x32_bf16(ahi, bl_[1][kk], acc1, 0, 0, 0);
      acc0 = __builtin_amdgcn_mfma_f32_16x16x32_bf16(alo, bh[0][kk], acc0, 0, 0, 0);
      acc1 = __builtin_amdgcn_mfma_f32_16x16x32_bf16(alo, bh[1][kk], acc1, 0, 0, 0);
    }
    // epilogue: C layout col=lane&15 (=i), row=(lane>>4)*4+q (=j within sub-tile)
#pragma unroll
    for (int q = 0; q < 4; ++q) {
      const int jl = w * 16 + (lane >> 4) * 4 + q;
      const int jgl = jt + jl;
      const float sj = sqj[cur][jl];
      float key0 = fmaf(-2.0f, acc0[q], sj);
      bool v0 = (jgl < jend) && (jgl >= jloI[0]) && (jgl < jhiI[0]) && (jgl != iG[0]);
      ins4(bd[0], bix[0], v0 ? key0 : BIGF, v0 ? jgl : IMAX);
      float key1 = fmaf(-2.0f, acc1[q], sj);
      bool v1 = (jgl < jend) && (jgl >= jloI[1]) && (jgl < jhiI[1]) && (jgl != iG[1]);
      ins4(bd[1], bix[1], v1 ? key1 : BIGF, v1 ? jgl : IMAX);
    }
    cur ^= 1;
  }

  // ---- merge across waves (overlay on bufA)
  __syncthreads();
  float (*cd)[68] = (float(*)[68])bufA;
  int (*ci)[68] = (int(*)[68])(bufA + 32 * 68 * 4);
#pragma unroll
  for (int ti = 0; ti < 2; ++ti) {
    int row = ti * 16 + (lane & 15);
    int slot = w * 16 + (lane >> 4) * 4;
#pragma unroll
    for (int q = 0; q < 4; ++q) {
      cd[row][slot + q] = bd[ti][q];
      ci[row][slot + q] = bix[ti][q];
    }
  }
  __syncthreads();
  if (t < 32) {
    float d[4] = {BIGF, BIGF, BIGF, BIGF};
    int ix[4] = {IMAX, IMAX, IMAX, IMAX};
    for (int e = 0; e < 64; ++e) ins4(d, ix, cd[t][e], ci[t][e]);
    const int i = i0 + t;
#pragma unroll
    for (int q = 0; q < 4; ++q) {
      candD[((size_t)hs * N_PTS + i) * 4 + q] = d[q];
      candI[((size_t)hs * N_PTS + i) * 4 + q] = ix[q];
    }
  }
}

__global__ __launch_bounds__(256) void knn_merge(const float* __restrict__ candD,
                                                 const int* __restrict__ candI,
                                                 int* __restrict__ idx_out) {
  const int i = blockIdx.x * 256 + threadIdx.x;
  float d[4] = {BIGF, BIGF, BIGF, BIGF};
  int ix[4] = {IMAX, IMAX, IMAX, IMAX};
#pragma unroll
  for (int h = 0; h < 4; ++h) {
    float4 dd = *(const float4*)&candD[((size_t)h * N_PTS + i) * 4];
    int4 ii = *(const int4*)&candI[((size_t)h * N_PTS + i) * 4];
    ins4(d, ix, dd.x, ii.x); ins4(d, ix, dd.y, ii.y);
    ins4(d, ix, dd.z, ii.z); ins4(d, ix, dd.w, ii.w);
  }
#pragma unroll
  for (int q = 0; q < 4; ++q) {
    int v = ix[q];
    if (v > N_PTS - 1) v = 0;  // OOB guard
    idx_out[i * 4 + q] = v;
  }
}

// ---------------------------------------------------------------- U/V GEMMs
__global__ __launch_bounds__(256) void uv_kernel(
    const float* __restrict__ X, const float* __restrict__ P,
    const float* __restrict__ Q, const float* __restrict__ bias,
    float* __restrict__ U, float* __restrict__ V) {
  __shared__ float xs[16][129];
  const int t = threadIdx.x;
  const int r0 = blockIdx.x * 16;
#pragma unroll
  for (int v = 0; v < 2; ++v) {
    int lin = t + v * 256;
    int r = lin >> 5, c4 = lin & 31;
    float4 val = *(const float4*)&X[(size_t)(r0 + r) * 128 + c4 * 4];
    xs[r][c4 * 4 + 0] = val.x; xs[r][c4 * 4 + 1] = val.y;
    xs[r][c4 * 4 + 2] = val.z; xs[r][c4 * 4 + 3] = val.w;
  }
  __syncthreads();
  const int cg = t & 31, rg = t >> 5;
  const int c0 = cg * 4;
  float4 b4 = *(const float4*)&bias[c0];
  float4 u0 = b4, u1 = b4;
  float4 v0 = make_float4(0, 0, 0, 0), v1 = make_float4(0, 0, 0, 0);
#pragma unroll 8
  for (int k = 0; k < 128; ++k) {
    float4 p = *(const float4*)&P[k * 128 + c0];
    float4 q = *(const float4*)&Q[k * 128 + c0];
    float xa = xs[rg * 2 + 0][k], xb = xs[rg * 2 + 1][k];
    u0.x = fmaf(xa, p.x, u0.x); u0.y = fmaf(xa, p.y, u0.y);
    u0.z = fmaf(xa, p.z, u0.z); u0.w = fmaf(xa, p.w, u0.w);
    u1.x = fmaf(xb, p.x, u1.x); u1.y = fmaf(xb, p.y, u1.y);
    u1.z = fmaf(xb, p.z, u1.z); u1.w = fmaf(xb, p.w, u1.w);
    v0.x = fmaf(xa, q.x, v0.x); v0.y = fmaf(xa, q.y, v0.y);
    v0.z = fmaf(xa, q.z, v0.z); v0.w = fmaf(xa, q.w, v0.w);
    v1.x = fmaf(xb, q.x, v1.x); v1.y = fmaf(xb, q.y, v1.y);
    v1.z = fmaf(xb, q.z, v1.z); v1.w = fmaf(xb, q.w, v1.w);
  }
  const int ra = r0 + rg * 2, rbw = ra + 1;
  *(float4*)&U[(size_t)ra * 128 + c0] = u0;
  *(float4*)&U[(size_t)rbw * 128 + c0] = u1;
  *(float4*)&V[(size_t)ra * 128 + c0] = v0;
  *(float4*)&V[(size_t)rbw * 128 + c0] = v1;
}

// ---------------------------------------------------------------- BN stats (deterministic)
// Per-block partials to ws; NO float atomics (they are order-nondeterministic
// and trip the graph-replay determinism check).
__global__ __launch_bounds__(256) void stats_kernel(
    const float* __restrict__ U, const float* __restrict__ V,
    const int* __restrict__ idx, float* __restrict__ part) {
  __shared__ float ps[2][128], ps2[2][128];
  const int t = threadIdx.x;
  const int c = t & 127, half = t >> 7;
  const int r0 = blockIdx.x * 64 + half * 32;
  float s = 0.0f, s2 = 0.0f;
  for (int rr = 0; rr < 32; ++rr) {
    const int i = r0 + rr;
    const float u = U[(size_t)i * 128 + c];
    const int4 jj = *(const int4*)&idx[i * 4];
    float h0 = elu_f(u + V[(size_t)jj.x * 128 + c]);
    float h1 = elu_f(u + V[(size_t)jj.y * 128 + c]);
    float h2 = elu_f(u + V[(size_t)jj.z * 128 + c]);
    float h3 = elu_f(u + V[(size_t)jj.w * 128 + c]);
    s += h0 + h1 + h2 + h3;
    s2 = fmaf(h0, h0, s2); s2 = fmaf(h1, h1, s2);
    s2 = fmaf(h2, h2, s2); s2 = fmaf(h3, h3, s2);
  }
  ps[half][c] = s; ps2[half][c] = s2;
  __syncthreads();
  if (t < 128) {
    part[blockIdx.x * 256 + t] = ps[0][t] + ps[1][t];
    part[blockIdx.x * 256 + 128 + t] = ps2[0][t] + ps2[1][t];
  }
}

// Fixed-order reduction over the 128 block partials -> deterministic BN stats.
__global__ void finalize_kernel(const float* __restrict__ part,
                                const float* __restrict__ g,
                                const float* __restrict__ bt,
                                float* __restrict__ sAB) {
  const int c = threadIdx.x;  // 128 threads
  float s = 0.0f, s2 = 0.0f;
  for (int b = 0; b < 128; ++b) {
    s += part[b * 256 + c];
    s2 += part[b * 256 + 128 + c];
  }
  const float inv_n = 1.0f / 32768.0f;
  float mean = s * inv_n;
  float var = s2 * inv_n - mean * mean;
  float inv = 1.0f / sqrtf(var + 1e-5f);
  float sA = g[c] * inv;
  sAB[c] = sA;
  sAB[128 + c] = bt[c] - mean * sA;
}

// ---------------------------------------------------------------- pass2
__global__ __launch_bounds__(256) void pass2_kernel(
    const float* __restrict__ U, const float* __restrict__ V,
    const int* __restrict__ idx, const float* __restrict__ sAB,
    const float* __restrict__ res, float* __restrict__ out) {
  const int t = threadIdx.x;
  const int c = t & 127, half = t >> 7;
  const int r0 = blockIdx.x * 64 + half * 32;
  const float sA = sAB[c], sB = sAB[128 + c];
  for (int rr = 0; rr < 32; ++rr) {
    const int i = r0 + rr;
    const float u = U[(size_t)i * 128 + c];
    const int4 jj = *(const int4*)&idx[i * 4];
    float m = fmaf(elu_f(u + V[(size_t)jj.x * 128 + c]), sA, sB);
    m = fmaxf(m, fmaf(elu_f(u + V[(size_t)jj.y * 128 + c]), sA, sB));
    m = fmaxf(m, fmaf(elu_f(u + V[(size_t)jj.z * 128 + c]), sA, sB));
    m = fmaxf(m, fmaf(elu_f(u + V[(size_t)jj.w * 128 + c]), sA, sB));
    if (res != nullptr) m += res[(size_t)i * 128 + c];
    out[(size_t)i * 128 + c] = m;
  }
}

// ---------------------------------------------------------------- output MLP
__global__ __launch_bounds__(256) void mlp_kernel(
    const float* __restrict__ F,
    const float* __restrict__ Wo1, const float* __restrict__ bo1,
    const float* __restrict__ Wo2, const float* __restrict__ bo2,
    const float* __restrict__ Wo3, const float* __restrict__ bo3,
    float* __restrict__ out) {
  __shared__ float xs[8][128];
  __shared__ float o1s[8][33];
  __shared__ float o2s[8][17];
  const int t = threadIdx.x;
  const int r0 = blockIdx.x * 8;
  {
    int r = t >> 5, c4 = t & 31;
    *(float4*)&xs[r][c4 * 4] = *(const float4*)&F[(size_t)(r0 + r) * 128 + c4 * 4];
  }
  __syncthreads();
  const int r = t >> 5, c = t & 31;
  {
    float acc = bo1[c];
    for (int j = 0; j < 128; ++j) acc = fmaf(xs[r][j], Wo1[j * 32 + c], acc);
    o1s[r][c] = elu_f(acc);
  }
  __syncthreads();
  if (c < 16) {
    float acc = bo2[c];
#pragma unroll
    for (int j = 0; j < 32; ++j) acc = fmaf(o1s[r][j], Wo2[j * 16 + c], acc);
    o2s[r][c] = elu_f(acc);
  }
  __syncthreads();
  if (c < 8) {
    float acc = bo3[c];
#pragma unroll
    for (int j = 0; j < 16; ++j) acc = fmaf(o2s[r][j], Wo3[j * 8 + c], acc);
    out[(size_t)(r0 + r) * 8 + c] = acc;
  }
}

// ---------------------------------------------------------------- launch
extern "C" void kernel_launch(void* const* d_in, const int* in_sizes, int n_in,
                              void* d_out, int out_size, void* d_ws, size_t ws_size,
                              hipStream_t stream) {
  (void)in_sizes; (void)n_in; (void)out_size; (void)ws_size;
  const float* x_lc = (const float*)d_in[0];
  const int* batch = (const int*)d_in[1];
  const float* We1 = (const float*)d_in[2];
  const float* be1 = (const float*)d_in[3];
  const float* We2 = (const float*)d_in[4];
  const float* be2 = (const float*)d_in[5];
  const float* Wc[3] = {(const float*)d_in[6], (const float*)d_in[10], (const float*)d_in[14]};
  const float* bc[3] = {(const float*)d_in[7], (const float*)d_in[11], (const float*)d_in[15]};
  const float* gg[3] = {(const float*)d_in[8], (const float*)d_in[12], (const float*)d_in[16]};
  const float* bt[3] = {(const float*)d_in[9], (const float*)d_in[13], (const float*)d_in[17]};
  const float* Wo1 = (const float*)d_in[18]; const float* bo1 = (const float*)d_in[19];
  const float* Wo2 = (const float*)d_in[20]; const float* bo2 = (const float*)d_in[21];
  const float* Wo3 = (const float*)d_in[22]; const float* bo3 = (const float*)d_in[23];
  float* out = (float*)d_out;

  float* ws = (float*)d_ws;
  float* featA = ws;                          // 8192*128
  float* featB = featA + N_PTS * HD;
  float* U = featB + N_PTS * HD;
  float* V = U + N_PTS * HD;
  float* sq = V + N_PTS * HD;                 // 8192
  float* Pb = sq + N_PTS;                     // 16384
  float* Qb = Pb + 16384;
  float* part = Qb + 16384;                   // 128*256 BN partials
  float* sAB = part + 128 * 256;              // 256
  float* candD = sAB + 256;                   // 4*8192*4
  int* candI = (int*)(candD + 4 * N_PTS * 4);
  int* idxb = candI + 4 * N_PTS * 4;          // 8192*4
  int* segs = idxb + N_PTS * 4;               // 5 (+pad)
  ushort* Xhi = (ushort*)(segs + 8);          // 8192*128 ushort
  ushort* Xlo = Xhi + N_PTS * HD;

  segs_kernel<<<1, 256, 0, stream>>>(batch, segs);
  encode_kernel<<<512, 128, 0, stream>>>(x_lc, We1, be1, We2, be2, featA);

  float* bufs[2] = {featA, featB};
  int cur = 0;
  for (int cc = 0; cc < 3; ++cc) {
    const float* Xc = bufs[cur];
    float* Onext = bufs[cur ^ 1];
    const float* rs = (cc == 0) ? nullptr : Xc;

    prep_pq<<<64, 256, 0, stream>>>(Wc[cc], Pb, Qb);
    rownorm_kernel<<<32, 256, 0, stream>>>(Xc, sq);
    tobf16_kernel<<<1024, 256, 0, stream>>>(Xc, Xhi, Xlo);
    knn_mfma_kernel<<<1024, 256, 0, stream>>>(Xhi, Xlo, segs, sq, candD, candI);
    knn_merge<<<32, 256, 0, stream>>>(candD, candI, idxb);
    uv_kernel<<<512, 256, 0, stream>>>(Xc, Pb, Qb, bc[cc], U, V);
    stats_kernel<<<128, 256, 0, stream>>>(U, V, idxb, part);
    finalize_kernel<<<1, 128, 0, stream>>>(part, gg[cc], bt[cc], sAB);
    pass2_kernel<<<128, 256, 0, stream>>>(U, V, idxb, sAB, rs, Onext);
    cur ^= 1;
  }

  mlp_kernel<<<1024, 256, 0, stream>>>(bufs[cur], Wo1, bo1, Wo2, bo2, Wo3, bo3, out);
}

// Round 12
// 697.802 us; speedup vs baseline: 1.5619x; 1.0781x over previous
//
#include <hip/hip_runtime.h>
#include <hip/hip_bf16.h>
#include <math.h>

#define N_PTS 8192
#define HD 128
#define BIGF 1e30f
#define IMAX 0x7fffffff

typedef __bf16 bf16x8 __attribute__((ext_vector_type(8)));
typedef float f32x4 __attribute__((ext_vector_type(4)));

__device__ __forceinline__ float elu_f(float x) {
  return x > 0.0f ? x : expm1f(x);
}

// ---------------------------------------------------------------- segments
__global__ void segs_kernel(const int* __restrict__ batch32, int* __restrict__ segs) {
  __shared__ int cnt[4];
  __shared__ int is64s;
  const int t = threadIdx.x;
  if (t < 4) cnt[t] = 0;
  if (t == 0) is64s = (batch32[8191] == 0) ? 1 : 0;  // int64: high word of elem 4095
  __syncthreads();
  const int is64 = is64s;
  for (int i = t; i < N_PTS; i += blockDim.x) {
    int b = is64 ? batch32[2 * i] : batch32[i];
    atomicAdd(&cnt[b], 1);  // integer atomic: exact, order-independent
  }
  __syncthreads();
  if (t == 0) {
    int s = 0; segs[0] = 0;
    for (int b = 0; b < 4; ++b) { s += cnt[b]; segs[b + 1] = s; }
  }
}

// ---------------------------------------------------------------- encode
__global__ __launch_bounds__(128) void encode_kernel(
    const float* __restrict__ x_lc,
    const float* __restrict__ We1, const float* __restrict__ be1,
    const float* __restrict__ We2, const float* __restrict__ be2,
    float* __restrict__ out) {
  __shared__ float xr[16 * 15];
  __shared__ float h1[16][128];
  const int r0 = blockIdx.x * 16;
  const int c = threadIdx.x;
  for (int tt = c; tt < 240; tt += 128) xr[tt] = x_lc[r0 * 15 + tt];
  __syncthreads();
  float acc[16];
#pragma unroll
  for (int r = 0; r < 16; ++r) acc[r] = be1[c];
  for (int j = 0; j < 15; ++j) {
    float w = We1[j * 128 + c];
#pragma unroll
    for (int r = 0; r < 16; ++r) acc[r] = fmaf(xr[r * 15 + j], w, acc[r]);
  }
#pragma unroll
  for (int r = 0; r < 16; ++r) h1[r][c] = elu_f(acc[r]);
  __syncthreads();
#pragma unroll
  for (int r = 0; r < 16; ++r) acc[r] = be2[c];
  for (int j0 = 0; j0 < 128; j0 += 4) {
    float w0 = We2[(j0 + 0) * 128 + c];
    float w1 = We2[(j0 + 1) * 128 + c];
    float w2 = We2[(j0 + 2) * 128 + c];
    float w3 = We2[(j0 + 3) * 128 + c];
#pragma unroll
    for (int r = 0; r < 16; ++r) {
      float4 h = *(const float4*)&h1[r][j0];
      acc[r] = fmaf(h.x, w0, acc[r]);
      acc[r] = fmaf(h.y, w1, acc[r]);
      acc[r] = fmaf(h.z, w2, acc[r]);
      acc[r] = fmaf(h.w, w3, acc[r]);
    }
  }
#pragma unroll
  for (int r = 0; r < 16; ++r) out[(r0 + r) * 128 + c] = elu_f(acc[r]);
}

// ---------------------------------------------------------------- prep_x: bf16 split + row norms (fused)
__global__ __launch_bounds__(256) void prep_x(const float* __restrict__ X,
                                              ushort* __restrict__ Xhi,
                                              ushort* __restrict__ Xlo,
                                              float* __restrict__ sq) {
  const int t = threadIdx.x;
  const int ln = t & 31;          // lane within 32-group (one row per group)
  const int g = t >> 5;           // 8 groups
  const int r = blockIdx.x * 8 + g;
  float4 v = *(const float4*)&X[(size_t)r * 128 + ln * 4];
  float vv[4] = {v.x, v.y, v.z, v.w};
  ushort h[4], l[4];
#pragma unroll
  for (int e = 0; e < 4; ++e) {
    __hip_bfloat16 hb = __float2bfloat16(vv[e]);
    float hf = __bfloat162float(hb);
    __hip_bfloat16 lb = __float2bfloat16(vv[e] - hf);
    h[e] = *(ushort*)&hb; l[e] = *(ushort*)&lb;
  }
  *(ushort4*)&Xhi[(size_t)r * 128 + ln * 4] = make_ushort4(h[0], h[1], h[2], h[3]);
  *(ushort4*)&Xlo[(size_t)r * 128 + ln * 4] = make_ushort4(l[0], l[1], l[2], l[3]);
  float s = v.x * v.x;
  s = fmaf(v.y, v.y, s); s = fmaf(v.z, v.z, s); s = fmaf(v.w, v.w, s);
#pragma unroll
  for (int off = 1; off < 32; off <<= 1) s += __shfl_xor(s, off);
  if (ln == 0) sq[r] = s;
}

// ---------------------------------------------------------------- P/Q prep, all 3 convs in one launch
__global__ void prep_pq_all(const float* __restrict__ W0, const float* __restrict__ W1,
                            const float* __restrict__ W2,
                            float* __restrict__ P, float* __restrict__ Q) {
  const int id = blockIdx.x * 256 + threadIdx.x;  // 49152
  const int cc = id >> 14, r = id & 16383;
  const float* W = (cc == 0) ? W0 : ((cc == 1) ? W1 : W2);
  const int k = r >> 7, c = r & 127;
  float top = W[k * 128 + c];
  float bot = W[(k + 128) * 128 + c];
  P[id] = top - bot;
  Q[id] = bot;
}

// ---------------------------------------------------------------- knn helpers
__device__ __forceinline__ bool lex_less(float da, int ia, float db, int ib) {
  return (da < db) || ((da == db) && (ia < ib));
}
__device__ __forceinline__ void ins4(float d[4], int ix[4], float nd, int ni) {
  if (lex_less(nd, ni, d[3], ix[3])) {
    d[3] = nd; ix[3] = ni;
    if (lex_less(d[3], ix[3], d[2], ix[2])) { float td=d[3];d[3]=d[2];d[2]=td; int ti=ix[3];ix[3]=ix[2];ix[2]=ti; }
    if (lex_less(d[2], ix[2], d[1], ix[1])) { float td=d[2];d[2]=d[1];d[1]=td; int ti=ix[2];ix[2]=ix[1];ix[1]=ti; }
    if (lex_less(d[1], ix[1], d[0], ix[0])) { float td=d[1];d[1]=d[0];d[0]=td; int ti=ix[1];ix[1]=ix[0];ix[0]=ti; }
  }
}

// ---------------------------------------------------------------- knn via MFMA, barrier-free
// Block: 32 i-rows (ib) x j-quarter (hs); 4 waves, wave w takes 16-j tiles
// strided by 64. A/B fragments loaded DIRECTLY from global (coalesced 16B/lane,
// identical lane->element map for A and B so k-permutation cancels). No staging
// LDS, no loop barriers. LDS = merge overlay only.
// NOTE: sq (row norms) MUST be loaded scalar — jt is segment-dependent and
// arbitrary mod 4, so a float4 load is misaligned UB and its N_PTS-4 clamp
// shifts indices for the last points (round-10 absmax failure).
__global__ __launch_bounds__(256, 2) void knn_mfma_kernel(
    const ushort* __restrict__ Xhi, const ushort* __restrict__ Xlo,
    const int* __restrict__ segs, const float* __restrict__ sq,
    float* __restrict__ candD, int* __restrict__ candI) {
  __shared__ __align__(16) char mbuf[17408];  // cd[32][68] f32 + ci[32][68] int

  const int t = threadIdx.x;
  const int w = t >> 6;
  const int lane = t & 63;
  const int ib = blockIdx.x >> 2;
  const int hs = blockIdx.x & 3;
  const int i0 = ib * 32;
  const int r15 = lane & 15;
  const int ch = lane >> 4;

  // per-i segment bounds
  int jloI[2], jhiI[2], iG[2];
#pragma unroll
  for (int a = 0; a < 2; ++a) {
    iG[a] = i0 + a * 16 + r15;
    int lo = 0, hi = 0;
#pragma unroll
    for (int b = 0; b < 4; ++b) {
      int s = segs[b], e = segs[b + 1];
      if (iG[a] >= s && iG[a] < e) { lo = s; hi = e; }
    }
    jloI[a] = lo; jhiI[a] = hi;
  }
  int jlo_blk = 0, jhi_blk = 0;
  {
    int bf = 0, bl = 0;
#pragma unroll
    for (int b = 0; b < 4; ++b) {
      int s = segs[b], e = segs[b + 1];
      if (i0 >= s && i0 < e) bf = b;
      if (i0 + 31 >= s && i0 + 31 < e) bl = b;
    }
    jlo_blk = segs[bf]; jhi_blk = segs[bl + 1];
  }
  const int len = jhi_blk - jlo_blk;
  const int qlen = (len + 3) >> 2;
  const int jstart = jlo_blk + hs * qlen;
  const int jend = min(jstart + qlen, jhi_blk);

  // B-fragments (xi): direct global loads, held in registers
  bf16x8 bh[2][4], bl_[2][4];
#pragma unroll
  for (int ti = 0; ti < 2; ++ti)
#pragma unroll
    for (int kk = 0; kk < 4; ++kk) {
      size_t off = (size_t)(i0 + ti * 16 + r15) * HD + (kk * 4 + ch) * 8;
      bh[ti][kk] = *(const bf16x8*)(Xhi + off);
      bl_[ti][kk] = *(const bf16x8*)(Xlo + off);
    }

  float bd[2][4]; int bix[2][4];
#pragma unroll
  for (int a = 0; a < 2; ++a)
#pragma unroll
    for (int q = 0; q < 4; ++q) { bd[a][q] = BIGF; bix[a][q] = IMAX; }

  // j loop: wave-strided 16-row tiles, all fragments in registers
#pragma unroll 2
  for (int jt = jstart + w * 16; jt < jend; jt += 64) {
    bf16x8 ah[4], al[4];
    const int jr = min(jt + r15, N_PTS - 1);
#pragma unroll
    for (int kk = 0; kk < 4; ++kk) {
      size_t off = (size_t)jr * HD + (kk * 4 + ch) * 8;
      ah[kk] = *(const bf16x8*)(Xhi + off);
      al[kk] = *(const bf16x8*)(Xlo + off);
    }
    // scalar, individually-clamped norm loads (exact index per output row)
    float sjv[4];
#pragma unroll
    for (int q = 0; q < 4; ++q)
      sjv[q] = sq[min(jt + ch * 4 + q, N_PTS - 1)];

    f32x4 acc0 = {0.f, 0.f, 0.f, 0.f}, acc1 = {0.f, 0.f, 0.f, 0.f};
#pragma unroll
    for (int kk = 0; kk < 4; ++kk) {
      acc0 = __builtin_amdgcn_mfma_f32_16x16x32_bf16(ah[kk], bh[0][kk], acc0, 0, 0, 0);
      acc1 = __builtin_amdgcn_mfma_f32_16x16x32_bf16(ah[kk], bh[1][kk], acc1, 0, 0, 0);
      acc0 = __builtin_amdgcn_mfma_f32_16x16x32_bf16(ah[kk], bl_[0][kk], acc0, 0, 0, 0);
      acc1 = __builtin_amdgcn_mfma_f32_16x16x32_bf16(ah[kk], bl_[1][kk], acc1, 0, 0, 0);
      acc0 = __builtin_amdgcn_mfma_f32_16x16x32_bf16(al[kk], bh[0][kk], acc0, 0, 0, 0);
      acc1 = __builtin_amdgcn_mfma_f32_16x16x32_bf16(al[kk], bh[1][kk], acc1, 0, 0, 0);
    }
    // C layout: col=lane&15 (=i), row=(lane>>4)*4+q (=j within tile)
#pragma unroll
    for (int q = 0; q < 4; ++q) {
      const int jgl = jt + ch * 4 + q;
      const float sj = sjv[q];
      float key0 = fmaf(-2.0f, acc0[q], sj);
      bool v0 = (jgl < jend) && (jgl >= jloI[0]) && (jgl < jhiI[0]) && (jgl != iG[0]);
      ins4(bd[0], bix[0], v0 ? key0 : BIGF, v0 ? jgl : IMAX);
      float key1 = fmaf(-2.0f, acc1[q], sj);
      bool v1 = (jgl < jend) && (jgl >= jloI[1]) && (jgl < jhiI[1]) && (jgl != iG[1]);
      ins4(bd[1], bix[1], v1 ? key1 : BIGF, v1 ? jgl : IMAX);
    }
  }

  // ---- merge across waves
  __syncthreads();
  float (*cd)[68] = (float(*)[68])mbuf;
  int (*ci)[68] = (int(*)[68])(mbuf + 32 * 68 * 4);
#pragma unroll
  for (int ti = 0; ti < 2; ++ti) {
    int row = ti * 16 + r15;
    int slot = w * 16 + ch * 4;
#pragma unroll
    for (int q = 0; q < 4; ++q) {
      cd[row][slot + q] = bd[ti][q];
      ci[row][slot + q] = bix[ti][q];
    }
  }
  __syncthreads();
  if (t < 32) {
    float d[4] = {BIGF, BIGF, BIGF, BIGF};
    int ix[4] = {IMAX, IMAX, IMAX, IMAX};
    for (int e = 0; e < 64; ++e) ins4(d, ix, cd[t][e], ci[t][e]);
    const int i = i0 + t;
#pragma unroll
    for (int q = 0; q < 4; ++q) {
      candD[((size_t)hs * N_PTS + i) * 4 + q] = d[q];
      candI[((size_t)hs * N_PTS + i) * 4 + q] = ix[q];
    }
  }
}

__global__ __launch_bounds__(256) void knn_merge(const float* __restrict__ candD,
                                                 const int* __restrict__ candI,
                                                 int* __restrict__ idx_out) {
  const int i = blockIdx.x * 256 + threadIdx.x;
  float d[4] = {BIGF, BIGF, BIGF, BIGF};
  int ix[4] = {IMAX, IMAX, IMAX, IMAX};
#pragma unroll
  for (int h = 0; h < 4; ++h) {
    float4 dd = *(const float4*)&candD[((size_t)h * N_PTS + i) * 4];
    int4 ii = *(const int4*)&candI[((size_t)h * N_PTS + i) * 4];
    ins4(d, ix, dd.x, ii.x); ins4(d, ix, dd.y, ii.y);
    ins4(d, ix, dd.z, ii.z); ins4(d, ix, dd.w, ii.w);
  }
#pragma unroll
  for (int q = 0; q < 4; ++q) {
    int v = ix[q];
    if (v > N_PTS - 1) v = 0;  // OOB guard
    idx_out[i * 4 + q] = v;
  }
}

// ---------------------------------------------------------------- U/V GEMMs
__global__ __launch_bounds__(256) void uv_kernel(
    const float* __restrict__ X, const float* __restrict__ P,
    const float* __restrict__ Q, const float* __restrict__ bias,
    float* __restrict__ U, float* __restrict__ V) {
  __shared__ float xs[16][129];
  const int t = threadIdx.x;
  const int r0 = blockIdx.x * 16;
#pragma unroll
  for (int v = 0; v < 2; ++v) {
    int lin = t + v * 256;
    int r = lin >> 5, c4 = lin & 31;
    float4 val = *(const float4*)&X[(size_t)(r0 + r) * 128 + c4 * 4];
    xs[r][c4 * 4 + 0] = val.x; xs[r][c4 * 4 + 1] = val.y;
    xs[r][c4 * 4 + 2] = val.z; xs[r][c4 * 4 + 3] = val.w;
  }
  __syncthreads();
  const int cg = t & 31, rg = t >> 5;
  const int c0 = cg * 4;
  float4 b4 = *(const float4*)&bias[c0];
  float4 u0 = b4, u1 = b4;
  float4 v0 = make_float4(0, 0, 0, 0), v1 = make_float4(0, 0, 0, 0);
#pragma unroll 8
  for (int k = 0; k < 128; ++k) {
    float4 p = *(const float4*)&P[k * 128 + c0];
    float4 q = *(const float4*)&Q[k * 128 + c0];
    float xa = xs[rg * 2 + 0][k], xb = xs[rg * 2 + 1][k];
    u0.x = fmaf(xa, p.x, u0.x); u0.y = fmaf(xa, p.y, u0.y);
    u0.z = fmaf(xa, p.z, u0.z); u0.w = fmaf(xa, p.w, u0.w);
    u1.x = fmaf(xb, p.x, u1.x); u1.y = fmaf(xb, p.y, u1.y);
    u1.z = fmaf(xb, p.z, u1.z); u1.w = fmaf(xb, p.w, u1.w);
    v0.x = fmaf(xa, q.x, v0.x); v0.y = fmaf(xa, q.y, v0.y);
    v0.z = fmaf(xa, q.z, v0.z); v0.w = fmaf(xa, q.w, v0.w);
    v1.x = fmaf(xb, q.x, v1.x); v1.y = fmaf(xb, q.y, v1.y);
    v1.w = fmaf(xb, q.w, v1.w); v1.z = fmaf(xb, q.z, v1.z);
  }
  const int ra = r0 + rg * 2, rbw = ra + 1;
  *(float4*)&U[(size_t)ra * 128 + c0] = u0;
  *(float4*)&U[(size_t)rbw * 128 + c0] = u1;
  *(float4*)&V[(size_t)ra * 128 + c0] = v0;
  *(float4*)&V[(size_t)rbw * 128 + c0] = v1;
}

// ---------------------------------------------------------------- BN stats (deterministic)
__global__ __launch_bounds__(256) void stats_kernel(
    const float* __restrict__ U, const float* __restrict__ V,
    const int* __restrict__ idx, float* __restrict__ part) {
  __shared__ float ps[2][128], ps2[2][128];
  const int t = threadIdx.x;
  const int c = t & 127, half = t >> 7;
  const int r0 = blockIdx.x * 64 + half * 32;
  float s = 0.0f, s2 = 0.0f;
  for (int rr = 0; rr < 32; ++rr) {
    const int i = r0 + rr;
    const float u = U[(size_t)i * 128 + c];
    const int4 jj = *(const int4*)&idx[i * 4];
    float h0 = elu_f(u + V[(size_t)jj.x * 128 + c]);
    float h1 = elu_f(u + V[(size_t)jj.y * 128 + c]);
    float h2 = elu_f(u + V[(size_t)jj.z * 128 + c]);
    float h3 = elu_f(u + V[(size_t)jj.w * 128 + c]);
    s += h0 + h1 + h2 + h3;
    s2 = fmaf(h0, h0, s2); s2 = fmaf(h1, h1, s2);
    s2 = fmaf(h2, h2, s2); s2 = fmaf(h3, h3, s2);
  }
  ps[half][c] = s; ps2[half][c] = s2;
  __syncthreads();
  if (t < 128) {
    part[blockIdx.x * 256 + t] = ps[0][t] + ps[1][t];
    part[blockIdx.x * 256 + 128 + t] = ps2[0][t] + ps2[1][t];
  }
}

// Fixed-order reduction over the 128 block partials -> deterministic BN stats.
__global__ void finalize_kernel(const float* __restrict__ part,
                                const float* __restrict__ g,
                                const float* __restrict__ bt,
                                float* __restrict__ sAB) {
  const int c = threadIdx.x;  // 128 threads
  float s = 0.0f, s2 = 0.0f;
  for (int b = 0; b < 128; ++b) {
    s += part[b * 256 + c];
    s2 += part[b * 256 + 128 + c];
  }
  const float inv_n = 1.0f / 32768.0f;
  float mean = s * inv_n;
  float var = s2 * inv_n - mean * mean;
  float inv = 1.0f / sqrtf(var + 1e-5f);
  float sA = g[c] * inv;
  sAB[c] = sA;
  sAB[128 + c] = bt[c] - mean * sA;
}

// ---------------------------------------------------------------- pass2
__global__ __launch_bounds__(256) void pass2_kernel(
    const float* __restrict__ U, const float* __restrict__ V,
    const int* __restrict__ idx, const float* __restrict__ sAB,
    const float* __restrict__ res, float* __restrict__ out) {
  const int t = threadIdx.x;
  const int c = t & 127, half = t >> 7;
  const int r0 = blockIdx.x * 64 + half * 32;
  const float sA = sAB[c], sB = sAB[128 + c];
  for (int rr = 0; rr < 32; ++rr) {
    const int i = r0 + rr;
    const float u = U[(size_t)i * 128 + c];
    const int4 jj = *(const int4*)&idx[i * 4];
    float m = fmaf(elu_f(u + V[(size_t)jj.x * 128 + c]), sA, sB);
    m = fmaxf(m, fmaf(elu_f(u + V[(size_t)jj.y * 128 + c]), sA, sB));
    m = fmaxf(m, fmaf(elu_f(u + V[(size_t)jj.z * 128 + c]), sA, sB));
    m = fmaxf(m, fmaf(elu_f(u + V[(size_t)jj.w * 128 + c]), sA, sB));
    if (res != nullptr) m += res[(size_t)i * 128 + c];
    out[(size_t)i * 128 + c] = m;
  }
}

// ---------------------------------------------------------------- output MLP
__global__ __launch_bounds__(256) void mlp_kernel(
    const float* __restrict__ F,
    const float* __restrict__ Wo1, const float* __restrict__ bo1,
    const float* __restrict__ Wo2, const float* __restrict__ bo2,
    const float* __restrict__ Wo3, const float* __restrict__ bo3,
    float* __restrict__ out) {
  __shared__ float xs[8][128];
  __shared__ float o1s[8][33];
  __shared__ float o2s[8][17];
  const int t = threadIdx.x;
  const int r0 = blockIdx.x * 8;
  {
    int r = t >> 5, c4 = t & 31;
    *(float4*)&xs[r][c4 * 4] = *(const float4*)&F[(size_t)(r0 + r) * 128 + c4 * 4];
  }
  __syncthreads();
  const int r = t >> 5, c = t & 31;
  {
    float acc = bo1[c];
    for (int j = 0; j < 128; ++j) acc = fmaf(xs[r][j], Wo1[j * 32 + c], acc);
    o1s[r][c] = elu_f(acc);
  }
  __syncthreads();
  if (c < 16) {
    float acc = bo2[c];
#pragma unroll
    for (int j = 0; j < 32; ++j) acc = fmaf(o1s[r][j], Wo2[j * 16 + c], acc);
    o2s[r][c] = elu_f(acc);
  }
  __syncthreads();
  if (c < 8) {
    float acc = bo3[c];
#pragma unroll
    for (int j = 0; j < 16; ++j) acc = fmaf(o2s[r][j], Wo3[j * 8 + c], acc);
    out[(size_t)(r0 + r) * 8 + c] = acc;
  }
}

// ---------------------------------------------------------------- launch
extern "C" void kernel_launch(void* const* d_in, const int* in_sizes, int n_in,
                              void* d_out, int out_size, void* d_ws, size_t ws_size,
                              hipStream_t stream) {
  (void)in_sizes; (void)n_in; (void)out_size; (void)ws_size;
  const float* x_lc = (const float*)d_in[0];
  const int* batch = (const int*)d_in[1];
  const float* We1 = (const float*)d_in[2];
  const float* be1 = (const float*)d_in[3];
  const float* We2 = (const float*)d_in[4];
  const float* be2 = (const float*)d_in[5];
  const float* Wc[3] = {(const float*)d_in[6], (const float*)d_in[10], (const float*)d_in[14]};
  const float* bc[3] = {(const float*)d_in[7], (const float*)d_in[11], (const float*)d_in[15]};
  const float* gg[3] = {(const float*)d_in[8], (const float*)d_in[12], (const float*)d_in[16]};
  const float* bt[3] = {(const float*)d_in[9], (const float*)d_in[13], (const float*)d_in[17]};
  const float* Wo1 = (const float*)d_in[18]; const float* bo1 = (const float*)d_in[19];
  const float* Wo2 = (const float*)d_in[20]; const float* bo2 = (const float*)d_in[21];
  const float* Wo3 = (const float*)d_in[22]; const float* bo3 = (const float*)d_in[23];
  float* out = (float*)d_out;

  float* ws = (float*)d_ws;
  float* featA = ws;                          // 8192*128
  float* featB = featA + N_PTS * HD;
  float* U = featB + N_PTS * HD;
  float* V = U + N_PTS * HD;
  float* sq = V + N_PTS * HD;                 // 8192
  float* Pb = sq + N_PTS;                     // 3*16384
  float* Qb = Pb + 3 * 16384;                 // 3*16384
  float* part = Qb + 3 * 16384;               // 128*256 BN partials
  float* sAB = part + 128 * 256;              // 256
  float* candD = sAB + 256;                   // 4*8192*4
  int* candI = (int*)(candD + 4 * N_PTS * 4);
  int* idxb = candI + 4 * N_PTS * 4;          // 8192*4
  int* segs = idxb + N_PTS * 4;               // 5 (+pad)
  ushort* Xhi = (ushort*)(segs + 8);          // 8192*128 ushort
  ushort* Xlo = Xhi + N_PTS * HD;

  segs_kernel<<<1, 256, 0, stream>>>(batch, segs);
  encode_kernel<<<512, 128, 0, stream>>>(x_lc, We1, be1, We2, be2, featA);
  prep_pq_all<<<192, 256, 0, stream>>>(Wc[0], Wc[1], Wc[2], Pb, Qb);

  float* bufs[2] = {featA, featB};
  int cur = 0;
  for (int cc = 0; cc < 3; ++cc) {
    const float* Xc = bufs[cur];
    float* Onext = bufs[cur ^ 1];
    const float* rs = (cc == 0) ? nullptr : Xc;

    prep_x<<<1024, 256, 0, stream>>>(Xc, Xhi, Xlo, sq);
    knn_mfma_kernel<<<1024, 256, 0, stream>>>(Xhi, Xlo, segs, sq, candD, candI);
    knn_merge<<<32, 256, 0, stream>>>(candD, candI, idxb);
    uv_kernel<<<512, 256, 0, stream>>>(Xc, Pb + cc * 16384, Qb + cc * 16384, bc[cc], U, V);
    stats_kernel<<<128, 256, 0, stream>>>(U, V, idxb, part);
    finalize_kernel<<<1, 128, 0, stream>>>(part, gg[cc], bt[cc], sAB);
    pass2_kernel<<<128, 256, 0, stream>>>(U, V, idxb, sAB, rs, Onext);
    cur ^= 1;
  }

  mlp_kernel<<<1024, 256, 0, stream>>>(bufs[cur], Wo1, bo1, Wo2, bo2, Wo3, bo3, out);
}